// Round 6
// baseline (307.874 us; speedup 1.0000x reference)
//
#include <hip/hip_runtime.h>
#include <hip/hip_bf16.h>

typedef __hip_bfloat16 bf16;
using s8v = __attribute__((ext_vector_type(8))) short;   // 8 x bf16 (4 VGPRs)
using s4v = __attribute__((ext_vector_type(4))) short;   // 4 x bf16 (8B)
using f4v = __attribute__((ext_vector_type(4))) float;   // 4 x fp32

#define D_MODEL 1024
#define NHEADS  16
#define HDIM    64
#define TSEQ    2048
#define NBATCH  2
#define BT      (NBATCH * TSEQ)   // 4096 rows

__device__ inline short f2bf_bits(float f) {
    bf16 h = __float2bfloat16(f);
    return *reinterpret_cast<short*>(&h);
}

// 8-element loaders -> bf16 bits (s8v). fp32 source converts on the fly.
__device__ inline void load8(const bf16* p, s8v& o) { o = *(const s8v*)p; }
__device__ inline void load8(const float* p, s8v& o) {
    const f4v a = *(const f4v*)p;
    const f4v b = *(const f4v*)(p + 4);
    s8v r;
    r[0] = f2bf_bits(a[0]); r[1] = f2bf_bits(a[1]);
    r[2] = f2bf_bits(a[2]); r[3] = f2bf_bits(a[3]);
    r[4] = f2bf_bits(b[0]); r[5] = f2bf_bits(b[1]);
    r[6] = f2bf_bits(b[2]); r[7] = f2bf_bits(b[3]);
    o = r;
}

__device__ inline void storeC(bf16* p, float v)  { *p = __float2bfloat16(v); }
__device__ inline void storeC(float* p, float v) { *p = v; }

// ---------------------------------------------------------------------------
// GEMM: C[m][n] = sum_k A[m][k] * W[n][k]   (einsum '...i,oi->...o')
// 128x128 tile / block, BK=64, 16x16x32 bf16 MFMA.
// If VT != nullptr, blockIdx.z==2 writes its output TRANSPOSED into VT as
// [b*1024 + col][t] (i.e. V^T per (b,head): [d][t]) via packed 8B stores.
// ---------------------------------------------------------------------------
template <typename TA, typename TW, typename TC>
__global__ __launch_bounds__(256) void gemm_bt(
    const TA* __restrict__ A,
    const TW* __restrict__ W0, const TW* __restrict__ W1, const TW* __restrict__ W2,
    TC* __restrict__ C0, TC* __restrict__ C1, TC* __restrict__ C2,
    bf16* __restrict__ VT)
{
    const TW* W = (blockIdx.z == 0) ? W0 : (blockIdx.z == 1) ? W1 : W2;
    TC*       C = (blockIdx.z == 0) ? C0 : (blockIdx.z == 1) ? C1 : C2;
    const bool vt_mode = (VT != nullptr) && (blockIdx.z == 2);

    constexpr int K = 1024, N = 1024;
    __shared__ __align__(16) short As[128 * 64];
    __shared__ __align__(16) short Ws[128 * 64];

    const int t    = threadIdx.x;
    const int lane = t & 63;
    const int wave = t >> 6;
    const int m16  = lane & 15;
    const int quad = lane >> 4;
    const int wm   = (wave >> 1) * 64;
    const int wn   = (wave & 1) * 64;
    const int rowBase = blockIdx.x * 128;
    const int colBase = blockIdx.y * 128;

    f4v acc[4][4];
#pragma unroll
    for (int i = 0; i < 4; ++i)
#pragma unroll
        for (int j = 0; j < 4; ++j) acc[i][j] = f4v{0.f, 0.f, 0.f, 0.f};

    for (int kk = 0; kk < K / 64; ++kk) {
#pragma unroll
        for (int r = 0; r < 4; ++r) {
            const int chunk = r * 256 + t;      // 0..1023
            const int row   = chunk >> 3;       // 0..127
            const int c8    = chunk & 7;        // 0..7
            s8v av, wv;
            load8(A + (size_t)(rowBase + row) * K + kk * 64 + c8 * 8, av);
            load8(W + (size_t)(colBase + row) * K + kk * 64 + c8 * 8, wv);
            *(s8v*)&As[chunk * 8] = av;
            *(s8v*)&Ws[chunk * 8] = wv;
        }
        __syncthreads();

#pragma unroll
        for (int ks = 0; ks < 2; ++ks) {
            s8v af[4], bw[4];
#pragma unroll
            for (int mt = 0; mt < 4; ++mt)
                af[mt] = *(const s8v*)&As[(wm + mt * 16 + m16) * 64 + ks * 32 + quad * 8];
#pragma unroll
            for (int nt = 0; nt < 4; ++nt)
                bw[nt] = *(const s8v*)&Ws[(wn + nt * 16 + m16) * 64 + ks * 32 + quad * 8];
#pragma unroll
            for (int mt = 0; mt < 4; ++mt)
#pragma unroll
                for (int nt = 0; nt < 4; ++nt)
                    acc[mt][nt] = __builtin_amdgcn_mfma_f32_16x16x32_bf16(
                        af[mt], bw[nt], acc[mt][nt], 0, 0, 0);
        }
        __syncthreads();
    }

    // epilogue: C/D layout col=lane&15, row=quad*4+reg (m89/m91-verified)
    if (vt_mode) {
        // write V^T: dst[(b*1024 + col)][t], 4 consecutive t per lane -> 8B store
#pragma unroll
        for (int mt = 0; mt < 4; ++mt)
#pragma unroll
            for (int nt = 0; nt < 4; ++nt) {
                const int col  = colBase + wn + nt * 16 + m16;       // h*64+d
                const int row0 = rowBase + wm + mt * 16 + quad * 4;  // global row
                const int bb   = row0 >> 11;                         // batch
                const int tt   = row0 & (TSEQ - 1);
                s4v pk;
#pragma unroll
                for (int r = 0; r < 4; ++r) pk[r] = f2bf_bits(acc[mt][nt][r]);
                *(s4v*)&VT[((size_t)(bb * 1024 + col)) * TSEQ + tt] = pk;
            }
    } else {
#pragma unroll
        for (int mt = 0; mt < 4; ++mt)
#pragma unroll
            for (int nt = 0; nt < 4; ++nt)
#pragma unroll
                for (int r = 0; r < 4; ++r) {
                    const int row = rowBase + wm + mt * 16 + quad * 4 + r;
                    const int col = colBase + wn + nt * 16 + m16;
                    storeC(&C[(size_t)row * N + col], acc[mt][nt][r]);
                }
    }
}

// ---------------------------------------------------------------------------
// RoPE applied IN-PLACE on q and k (bf16, [B, T, D_MODEL] layout).
// ---------------------------------------------------------------------------
__global__ __launch_bounds__(256) void rope_inplace(
    bf16* __restrict__ qp, bf16* __restrict__ kp)
{
    const int idx = blockIdx.x * 256 + threadIdx.x;   // 0 .. 2^21-1
    const int i  = idx & 31;
    const int h  = (idx >> 5) & (NHEADS - 1);
    const int tt = (idx >> 9) & (TSEQ - 1);
    const int b  = idx >> 20;

    const size_t src = (size_t)(b * TSEQ + tt) * D_MODEL + h * HDIM + 2 * i;

    const float inv_freq = expf(-(float)i * (9.210340371976184f / 32.0f));
    const float f = (float)tt * inv_freq;
    float s, c;
    sincosf(f, &s, &c);

    const float q1 = __bfloat162float(qp[src]);
    const float q2 = __bfloat162float(qp[src + 1]);
    qp[src]     = __float2bfloat16(q1 * c - q2 * s);
    qp[src + 1] = __float2bfloat16(q1 * s + q2 * c);

    const float k1 = __bfloat162float(kp[src]);
    const float k2 = __bfloat162float(kp[src + 1]);
    kp[src]     = __float2bfloat16(k1 * c - k2 * s);
    kp[src + 1] = __float2bfloat16(k1 * s + k2 * c);
}

// ---------------------------------------------------------------------------
// Flash attention v3 (causal). Q/K in [B,T,D]; V^T in [b*1024+h*64+d][t].
// XCD-AWARE SWIZZLE: grid is 1-D (512); hb = blockIdx.x & 31 selects (b,h),
// ib = blockIdx.x >> 5 selects the q-tile pair. Blocks of the same (b,h)
// differ by multiples of 32 (= 0 mod 8) in linear index -> round-robin
// dispatch places them all on ONE XCD, so each head's 512 KB of K+V^T is
// fetched into that XCD's L2 once instead of 8x.
// Block = 4 waves; wave owns 16 q-rows; q-tile 64. Each block processes TWO
// q-tiles (ib and 31-ib) for perfect triangle balance. kv walked in 128-chunks.
// NO barriers: P round-trips through per-wave LDS with in-wave lgkmcnt wait.
// Mask only on the last (diagonal) kv iteration. Output in-place into qp.
// ---------------------------------------------------------------------------
__global__ __launch_bounds__(256) void attn_kernel(
    bf16* __restrict__ qp, const bf16* __restrict__ kp,
    const bf16* __restrict__ vt)
{
    const int hb = blockIdx.x & 31;    // (b,h) pair -> fixes XCD
    const int ib = blockIdx.x >> 5;    // 0..15 -> q-tile pair (ib, 31-ib)
    const int h  = hb & (NHEADS - 1);
    const int b  = hb >> 4;
    const int t    = threadIdx.x;
    const int lane = t & 63;
    const int wave = t >> 6;
    const int m16  = lane & 15;
    const int quad = lane >> 4;

    bf16*       Qb  = qp + (size_t)b * TSEQ * D_MODEL + h * HDIM;
    const bf16* Kb  = kp + (size_t)b * TSEQ * D_MODEL + h * HDIM;
    const bf16* Vtb = vt + ((size_t)b * 1024 + h * HDIM) * TSEQ;

    __shared__ __align__(16) short P_lds[4][16][136];   // per-wave P[16][128], +8 pad

#pragma unroll 1
    for (int pass = 0; pass < 2; ++pass) {
        const int bx = pass ? (31 - ib) : ib;
        const int q0 = bx * 64 + wave * 16;

        const s8v aq0 = *(const s8v*)&Qb[(size_t)(q0 + m16) * D_MODEL + quad * 8];
        const s8v aq1 = *(const s8v*)&Qb[(size_t)(q0 + m16) * D_MODEL + 32 + quad * 8];

        f4v o_acc[4];
#pragma unroll
        for (int nd = 0; nd < 4; ++nd) o_acc[nd] = f4v{0.f, 0.f, 0.f, 0.f};
        float m_run[4], l_run[4];
#pragma unroll
        for (int r = 0; r < 4; ++r) { m_run[r] = -1e30f; l_run[r] = 0.f; }

        const int iters = (bx + 2) >> 1;   // kv-128 steps
#pragma unroll 1
        for (int it = 0; it < iters; ++it) {
            const int kv0 = it * 128;

            // S = Q K^T over 128 kv cols (8 n-tiles x 2 k)
            f4v s_acc[8];
#pragma unroll
            for (int nk = 0; nk < 8; ++nk) s_acc[nk] = f4v{0.f, 0.f, 0.f, 0.f};
#pragma unroll
            for (int nk = 0; nk < 8; ++nk) {
                const s8v bk0 = *(const s8v*)&Kb[(size_t)(kv0 + nk * 16 + m16) * D_MODEL + quad * 8];
                const s8v bk1 = *(const s8v*)&Kb[(size_t)(kv0 + nk * 16 + m16) * D_MODEL + 32 + quad * 8];
                s_acc[nk] = __builtin_amdgcn_mfma_f32_16x16x32_bf16(aq0, bk0, s_acc[nk], 0, 0, 0);
                s_acc[nk] = __builtin_amdgcn_mfma_f32_16x16x32_bf16(aq1, bk1, s_acc[nk], 0, 0, 0);
            }

            // issue V^T fragment loads early (overlap with softmax)
            s8v bv[4][4];   // [d-tile][k-tile], 16B contiguous in t
#pragma unroll
            for (int nd = 0; nd < 4; ++nd)
#pragma unroll
                for (int kt = 0; kt < 4; ++kt)
                    bv[nd][kt] = *(const s8v*)&Vtb[(size_t)(nd * 16 + m16) * TSEQ
                                                   + kv0 + kt * 32 + quad * 8];

            // scale + (diagonal-only) mask + row max
            float lm[4];
#pragma unroll
            for (int r = 0; r < 4; ++r) lm[r] = -1e30f;
            const bool diag = (it == iters - 1);
#pragma unroll
            for (int nk = 0; nk < 8; ++nk) {
                const int kv = kv0 + nk * 16 + m16;
#pragma unroll
                for (int r = 0; r < 4; ++r) {
                    float s = s_acc[nk][r] * 0.125f;
                    if (diag) {
                        const int qi = q0 + quad * 4 + r;
                        s = (kv <= qi) ? s : -1e30f;
                    }
                    s_acc[nk][r] = s;
                    lm[r] = fmaxf(lm[r], s);
                }
            }
#pragma unroll
            for (int off = 8; off >= 1; off >>= 1)
#pragma unroll
                for (int r = 0; r < 4; ++r)
                    lm[r] = fmaxf(lm[r], __shfl_xor(lm[r], off, 64));

            float alpha[4], ls[4];
#pragma unroll
            for (int r = 0; r < 4; ++r) {
                const float mn = fmaxf(m_run[r], lm[r]);
                alpha[r] = __expf(m_run[r] - mn);
                m_run[r] = mn;
                ls[r] = 0.f;
            }
#pragma unroll
            for (int nk = 0; nk < 8; ++nk)
#pragma unroll
                for (int r = 0; r < 4; ++r) {
                    const float p = __expf(s_acc[nk][r] - m_run[r]);
                    s_acc[nk][r] = p;
                    ls[r] += p;
                }
#pragma unroll
            for (int off = 8; off >= 1; off >>= 1)
#pragma unroll
                for (int r = 0; r < 4; ++r)
                    ls[r] += __shfl_xor(ls[r], off, 64);
#pragma unroll
            for (int r = 0; r < 4; ++r) l_run[r] = l_run[r] * alpha[r] + ls[r];
#pragma unroll
            for (int nd = 0; nd < 4; ++nd)
#pragma unroll
                for (int r = 0; r < 4; ++r) o_acc[nd][r] *= alpha[r];

            // P: C-layout -> per-wave LDS -> A-layout (in-wave; no barrier)
#pragma unroll
            for (int nk = 0; nk < 8; ++nk)
#pragma unroll
                for (int r = 0; r < 4; ++r)
                    P_lds[wave][quad * 4 + r][nk * 16 + m16] = f2bf_bits(s_acc[nk][r]);
            asm volatile("s_waitcnt lgkmcnt(0)" ::: "memory");
            s8v ap[4];
#pragma unroll
            for (int kt = 0; kt < 4; ++kt)
                ap[kt] = *(const s8v*)&P_lds[wave][m16][kt * 32 + quad * 8];

            // O += P V  (4 d-tiles x 4 k-tiles)
#pragma unroll
            for (int nd = 0; nd < 4; ++nd)
#pragma unroll
                for (int kt = 0; kt < 4; ++kt)
                    o_acc[nd] = __builtin_amdgcn_mfma_f32_16x16x32_bf16(
                        ap[kt], bv[nd][kt], o_acc[nd], 0, 0, 0);
        }

        // epilogue: divide by denom, write IN-PLACE into qp (own region)
#pragma unroll
        for (int nd = 0; nd < 4; ++nd)
#pragma unroll
            for (int r = 0; r < 4; ++r) {
                const int qi = q0 + quad * 4 + r;
                Qb[(size_t)qi * D_MODEL + nd * 16 + m16] =
                    __float2bfloat16(o_acc[nd][r] / l_run[r]);
            }
    }
}

// ---------------------------------------------------------------------------
extern "C" void kernel_launch(void* const* d_in, const int* in_sizes, int n_in,
                              void* d_out, int out_size, void* d_ws, size_t ws_size,
                              hipStream_t stream) {
    const float* x  = (const float*)d_in[0];   // fp32 inputs
    const float* wq = (const float*)d_in[1];
    const float* wk = (const float*)d_in[2];
    const float* wv = (const float*)d_in[3];
    const float* wo = (const float*)d_in[4];
    float* out = (float*)d_out;                // fp32 output, 16 MB

    bf16* ws = (bf16*)d_ws;
    const size_t SZ = (size_t)BT * D_MODEL;    // 4M elems = 8MB bf16
    bf16* qp = ws + 0 * SZ;                    // total ws use: 16 MB
    bf16* kp = ws + 1 * SZ;
    bf16* vt = (bf16*)d_out;  // V^T (8 MB bf16) parked in d_out; dead before stage 4

    // 1. fused QKV projections; z==2 (V) written transposed into vt
    gemm_bt<float, float, bf16><<<dim3(32, 8, 3), 256, 0, stream>>>(
        x, wq, wk, wv, qp, kp, qp /*unused*/, vt);
    // 2. RoPE in place on q and k (bf16)
    rope_inplace<<<dim3(8192), 256, 0, stream>>>(qp, kp);
    // 3. causal flash attention (XCD-swizzled); output in-place into qp
    attn_kernel<<<dim3(512), 256, 0, stream>>>(qp, kp, vt);
    // 4. output projection: qp (bf16) x wo (fp32) -> d_out (fp32)
    gemm_bt<bf16, float, float><<<dim3(32, 8, 1), 256, 0, stream>>>(
        qp, wo, wo, wo, out, out, out, nullptr);
}

// Round 7
// 290.128 us; speedup vs baseline: 1.0612x; 1.0612x over previous
//
#include <hip/hip_runtime.h>
#include <hip/hip_bf16.h>

typedef __hip_bfloat16 bf16;
using s8v = __attribute__((ext_vector_type(8))) short;   // 8 x bf16 (4 VGPRs)
using s4v = __attribute__((ext_vector_type(4))) short;   // 4 x bf16 (8B)
using f4v = __attribute__((ext_vector_type(4))) float;   // 4 x fp32

#define D_MODEL 1024
#define NHEADS  16
#define HDIM    64
#define TSEQ    2048
#define NBATCH  2
#define BT      (NBATCH * TSEQ)   // 4096 rows

__device__ inline short f2bf_bits(float f) {
    bf16 h = __float2bfloat16(f);
    return *reinterpret_cast<short*>(&h);
}

// 8-element loaders -> bf16 bits (s8v). fp32 source converts on the fly.
__device__ inline void load8(const bf16* p, s8v& o) { o = *(const s8v*)p; }
__device__ inline void load8(const float* p, s8v& o) {
    const f4v a = *(const f4v*)p;
    const f4v b = *(const f4v*)(p + 4);
    s8v r;
    r[0] = f2bf_bits(a[0]); r[1] = f2bf_bits(a[1]);
    r[2] = f2bf_bits(a[2]); r[3] = f2bf_bits(a[3]);
    r[4] = f2bf_bits(b[0]); r[5] = f2bf_bits(b[1]);
    r[6] = f2bf_bits(b[2]); r[7] = f2bf_bits(b[3]);
    o = r;
}

__device__ inline void storeC(bf16* p, float v)  { *p = __float2bfloat16(v); }
__device__ inline void storeC(float* p, float v) { *p = v; }

// ---------------------------------------------------------------------------
// GEMM: C[m][n] = sum_k A[m][k] * W[n][k]   (einsum '...i,oi->...o')
// 128x128 tile / block, BK=64, 16x16x32 bf16 MFMA.
// __launch_bounds__(256, 2): min 2 waves/EU -> VGPR cap 256 (was implicitly
// 112 = 4-waves default, which SPILLED the 64-VGPR accumulator tile).
// If VT != nullptr, blockIdx.z==2 writes its output TRANSPOSED into VT as
// [b*1024 + col][t] (i.e. V^T per (b,head): [d][t]) via packed 8B stores.
// ---------------------------------------------------------------------------
template <typename TA, typename TW, typename TC>
__global__ __launch_bounds__(256, 2) void gemm_bt(
    const TA* __restrict__ A,
    const TW* __restrict__ W0, const TW* __restrict__ W1, const TW* __restrict__ W2,
    TC* __restrict__ C0, TC* __restrict__ C1, TC* __restrict__ C2,
    bf16* __restrict__ VT)
{
    const TW* W = (blockIdx.z == 0) ? W0 : (blockIdx.z == 1) ? W1 : W2;
    TC*       C = (blockIdx.z == 0) ? C0 : (blockIdx.z == 1) ? C1 : C2;
    const bool vt_mode = (VT != nullptr) && (blockIdx.z == 2);

    constexpr int K = 1024, N = 1024;
    __shared__ __align__(16) short As[128 * 64];
    __shared__ __align__(16) short Ws[128 * 64];

    const int t    = threadIdx.x;
    const int lane = t & 63;
    const int wave = t >> 6;
    const int m16  = lane & 15;
    const int quad = lane >> 4;
    const int wm   = (wave >> 1) * 64;
    const int wn   = (wave & 1) * 64;
    const int rowBase = blockIdx.x * 128;
    const int colBase = blockIdx.y * 128;

    f4v acc[4][4];
#pragma unroll
    for (int i = 0; i < 4; ++i)
#pragma unroll
        for (int j = 0; j < 4; ++j) acc[i][j] = f4v{0.f, 0.f, 0.f, 0.f};

    for (int kk = 0; kk < K / 64; ++kk) {
#pragma unroll
        for (int r = 0; r < 4; ++r) {
            const int chunk = r * 256 + t;      // 0..1023
            const int row   = chunk >> 3;       // 0..127
            const int c8    = chunk & 7;        // 0..7
            s8v av, wv;
            load8(A + (size_t)(rowBase + row) * K + kk * 64 + c8 * 8, av);
            load8(W + (size_t)(colBase + row) * K + kk * 64 + c8 * 8, wv);
            *(s8v*)&As[chunk * 8] = av;
            *(s8v*)&Ws[chunk * 8] = wv;
        }
        __syncthreads();

#pragma unroll
        for (int ks = 0; ks < 2; ++ks) {
            s8v af[4], bw[4];
#pragma unroll
            for (int mt = 0; mt < 4; ++mt)
                af[mt] = *(const s8v*)&As[(wm + mt * 16 + m16) * 64 + ks * 32 + quad * 8];
#pragma unroll
            for (int nt = 0; nt < 4; ++nt)
                bw[nt] = *(const s8v*)&Ws[(wn + nt * 16 + m16) * 64 + ks * 32 + quad * 8];
#pragma unroll
            for (int mt = 0; mt < 4; ++mt)
#pragma unroll
                for (int nt = 0; nt < 4; ++nt)
                    acc[mt][nt] = __builtin_amdgcn_mfma_f32_16x16x32_bf16(
                        af[mt], bw[nt], acc[mt][nt], 0, 0, 0);
        }
        __syncthreads();
    }

    // epilogue: C/D layout col=lane&15, row=quad*4+reg (m89/m91-verified)
    if (vt_mode) {
        // write V^T: dst[(b*1024 + col)][t], 4 consecutive t per lane -> 8B store
#pragma unroll
        for (int mt = 0; mt < 4; ++mt)
#pragma unroll
            for (int nt = 0; nt < 4; ++nt) {
                const int col  = colBase + wn + nt * 16 + m16;       // h*64+d
                const int row0 = rowBase + wm + mt * 16 + quad * 4;  // global row
                const int bb   = row0 >> 11;                         // batch
                const int tt   = row0 & (TSEQ - 1);
                s4v pk;
#pragma unroll
                for (int r = 0; r < 4; ++r) pk[r] = f2bf_bits(acc[mt][nt][r]);
                *(s4v*)&VT[((size_t)(bb * 1024 + col)) * TSEQ + tt] = pk;
            }
    } else {
#pragma unroll
        for (int mt = 0; mt < 4; ++mt)
#pragma unroll
            for (int nt = 0; nt < 4; ++nt)
#pragma unroll
                for (int r = 0; r < 4; ++r) {
                    const int row = rowBase + wm + mt * 16 + quad * 4 + r;
                    const int col = colBase + wn + nt * 16 + m16;
                    storeC(&C[(size_t)row * N + col], acc[mt][nt][r]);
                }
    }
}

// ---------------------------------------------------------------------------
// RoPE applied IN-PLACE on q and k (bf16, [B, T, D_MODEL] layout).
// ---------------------------------------------------------------------------
__global__ __launch_bounds__(256) void rope_inplace(
    bf16* __restrict__ qp, bf16* __restrict__ kp)
{
    const int idx = blockIdx.x * 256 + threadIdx.x;   // 0 .. 2^21-1
    const int i  = idx & 31;
    const int h  = (idx >> 5) & (NHEADS - 1);
    const int tt = (idx >> 9) & (TSEQ - 1);
    const int b  = idx >> 20;

    const size_t src = (size_t)(b * TSEQ + tt) * D_MODEL + h * HDIM + 2 * i;

    const float inv_freq = expf(-(float)i * (9.210340371976184f / 32.0f));
    const float f = (float)tt * inv_freq;
    float s, c;
    sincosf(f, &s, &c);

    const float q1 = __bfloat162float(qp[src]);
    const float q2 = __bfloat162float(qp[src + 1]);
    qp[src]     = __float2bfloat16(q1 * c - q2 * s);
    qp[src + 1] = __float2bfloat16(q1 * s + q2 * c);

    const float k1 = __bfloat162float(kp[src]);
    const float k2 = __bfloat162float(kp[src + 1]);
    kp[src]     = __float2bfloat16(k1 * c - k2 * s);
    kp[src + 1] = __float2bfloat16(k1 * s + k2 * c);
}

// ---------------------------------------------------------------------------
// Flash attention v3 (causal). Q/K in [B,T,D]; V^T in [b*1024+h*64+d][t].
// XCD swizzle: hb = blockIdx.x & 31 -> (b,h) fixed per XCD; ib = q-tile pair.
// __launch_bounds__(256, 2): VGPR cap 256 (was 112-default -> ~60 spilled
// VGPRs -> scratch round-trips dominated at ~18K cyc/iter).
// Block = 4 waves; wave owns 16 q-rows; two q-tiles (ib, 31-ib) per block.
// kv in 128-chunks; no barriers (per-wave P LDS + in-wave lgkmcnt wait).
// ---------------------------------------------------------------------------
__global__ __launch_bounds__(256, 2) void attn_kernel(
    bf16* __restrict__ qp, const bf16* __restrict__ kp,
    const bf16* __restrict__ vt)
{
    const int hb = blockIdx.x & 31;    // (b,h) pair -> fixes XCD
    const int ib = blockIdx.x >> 5;    // 0..15 -> q-tile pair (ib, 31-ib)
    const int h  = hb & (NHEADS - 1);
    const int b  = hb >> 4;
    const int t    = threadIdx.x;
    const int lane = t & 63;
    const int wave = t >> 6;
    const int m16  = lane & 15;
    const int quad = lane >> 4;

    bf16*       Qb  = qp + (size_t)b * TSEQ * D_MODEL + h * HDIM;
    const bf16* Kb  = kp + (size_t)b * TSEQ * D_MODEL + h * HDIM;
    const bf16* Vtb = vt + ((size_t)b * 1024 + h * HDIM) * TSEQ;

    __shared__ __align__(16) short P_lds[4][16][136];   // per-wave P[16][128], +8 pad

#pragma unroll 1
    for (int pass = 0; pass < 2; ++pass) {
        const int bx = pass ? (31 - ib) : ib;
        const int q0 = bx * 64 + wave * 16;

        const s8v aq0 = *(const s8v*)&Qb[(size_t)(q0 + m16) * D_MODEL + quad * 8];
        const s8v aq1 = *(const s8v*)&Qb[(size_t)(q0 + m16) * D_MODEL + 32 + quad * 8];

        f4v o_acc[4];
#pragma unroll
        for (int nd = 0; nd < 4; ++nd) o_acc[nd] = f4v{0.f, 0.f, 0.f, 0.f};
        float m_run[4], l_run[4];
#pragma unroll
        for (int r = 0; r < 4; ++r) { m_run[r] = -1e30f; l_run[r] = 0.f; }

        const int iters = (bx + 2) >> 1;   // kv-128 steps
#pragma unroll 1
        for (int it = 0; it < iters; ++it) {
            const int kv0 = it * 128;

            // S = Q K^T over 128 kv cols (8 n-tiles x 2 k)
            f4v s_acc[8];
#pragma unroll
            for (int nk = 0; nk < 8; ++nk) s_acc[nk] = f4v{0.f, 0.f, 0.f, 0.f};
#pragma unroll
            for (int nk = 0; nk < 8; ++nk) {
                const s8v bk0 = *(const s8v*)&Kb[(size_t)(kv0 + nk * 16 + m16) * D_MODEL + quad * 8];
                const s8v bk1 = *(const s8v*)&Kb[(size_t)(kv0 + nk * 16 + m16) * D_MODEL + 32 + quad * 8];
                s_acc[nk] = __builtin_amdgcn_mfma_f32_16x16x32_bf16(aq0, bk0, s_acc[nk], 0, 0, 0);
                s_acc[nk] = __builtin_amdgcn_mfma_f32_16x16x32_bf16(aq1, bk1, s_acc[nk], 0, 0, 0);
            }

            // issue V^T fragment loads early (overlap with softmax)
            s8v bv[4][4];   // [d-tile][k-tile], 16B contiguous in t
#pragma unroll
            for (int nd = 0; nd < 4; ++nd)
#pragma unroll
                for (int kt = 0; kt < 4; ++kt)
                    bv[nd][kt] = *(const s8v*)&Vtb[(size_t)(nd * 16 + m16) * TSEQ
                                                   + kv0 + kt * 32 + quad * 8];

            // scale + (diagonal-only) mask + row max
            float lm[4];
#pragma unroll
            for (int r = 0; r < 4; ++r) lm[r] = -1e30f;
            const bool diag = (it == iters - 1);
#pragma unroll
            for (int nk = 0; nk < 8; ++nk) {
                const int kv = kv0 + nk * 16 + m16;
#pragma unroll
                for (int r = 0; r < 4; ++r) {
                    float s = s_acc[nk][r] * 0.125f;
                    if (diag) {
                        const int qi = q0 + quad * 4 + r;
                        s = (kv <= qi) ? s : -1e30f;
                    }
                    s_acc[nk][r] = s;
                    lm[r] = fmaxf(lm[r], s);
                }
            }
#pragma unroll
            for (int off = 8; off >= 1; off >>= 1)
#pragma unroll
                for (int r = 0; r < 4; ++r)
                    lm[r] = fmaxf(lm[r], __shfl_xor(lm[r], off, 64));

            float alpha[4], ls[4];
#pragma unroll
            for (int r = 0; r < 4; ++r) {
                const float mn = fmaxf(m_run[r], lm[r]);
                alpha[r] = __expf(m_run[r] - mn);
                m_run[r] = mn;
                ls[r] = 0.f;
            }
#pragma unroll
            for (int nk = 0; nk < 8; ++nk)
#pragma unroll
                for (int r = 0; r < 4; ++r) {
                    const float p = __expf(s_acc[nk][r] - m_run[r]);
                    s_acc[nk][r] = p;
                    ls[r] += p;
                }
#pragma unroll
            for (int off = 8; off >= 1; off >>= 1)
#pragma unroll
                for (int r = 0; r < 4; ++r)
                    ls[r] += __shfl_xor(ls[r], off, 64);
#pragma unroll
            for (int r = 0; r < 4; ++r) l_run[r] = l_run[r] * alpha[r] + ls[r];
#pragma unroll
            for (int nd = 0; nd < 4; ++nd)
#pragma unroll
                for (int r = 0; r < 4; ++r) o_acc[nd][r] *= alpha[r];

            // P: C-layout -> per-wave LDS -> A-layout (in-wave; no barrier)
#pragma unroll
            for (int nk = 0; nk < 8; ++nk)
#pragma unroll
                for (int r = 0; r < 4; ++r)
                    P_lds[wave][quad * 4 + r][nk * 16 + m16] = f2bf_bits(s_acc[nk][r]);
            asm volatile("s_waitcnt lgkmcnt(0)" ::: "memory");
            s8v ap[4];
#pragma unroll
            for (int kt = 0; kt < 4; ++kt)
                ap[kt] = *(const s8v*)&P_lds[wave][m16][kt * 32 + quad * 8];

            // O += P V  (4 d-tiles x 4 k-tiles)
#pragma unroll
            for (int nd = 0; nd < 4; ++nd)
#pragma unroll
                for (int kt = 0; kt < 4; ++kt)
                    o_acc[nd] = __builtin_amdgcn_mfma_f32_16x16x32_bf16(
                        ap[kt], bv[nd][kt], o_acc[nd], 0, 0, 0);
        }

        // epilogue: divide by denom, write IN-PLACE into qp (own region)
#pragma unroll
        for (int nd = 0; nd < 4; ++nd)
#pragma unroll
            for (int r = 0; r < 4; ++r) {
                const int qi = q0 + quad * 4 + r;
                Qb[(size_t)qi * D_MODEL + nd * 16 + m16] =
                    __float2bfloat16(o_acc[nd][r] / l_run[r]);
            }
    }
}

// ---------------------------------------------------------------------------
extern "C" void kernel_launch(void* const* d_in, const int* in_sizes, int n_in,
                              void* d_out, int out_size, void* d_ws, size_t ws_size,
                              hipStream_t stream) {
    const float* x  = (const float*)d_in[0];   // fp32 inputs
    const float* wq = (const float*)d_in[1];
    const float* wk = (const float*)d_in[2];
    const float* wv = (const float*)d_in[3];
    const float* wo = (const float*)d_in[4];
    float* out = (float*)d_out;                // fp32 output, 16 MB

    bf16* ws = (bf16*)d_ws;
    const size_t SZ = (size_t)BT * D_MODEL;    // 4M elems = 8MB bf16
    bf16* qp = ws + 0 * SZ;                    // total ws use: 16 MB
    bf16* kp = ws + 1 * SZ;
    bf16* vt = (bf16*)d_out;  // V^T (8 MB bf16) parked in d_out; dead before stage 4

    // 1. fused QKV projections; z==2 (V) written transposed into vt
    gemm_bt<float, float, bf16><<<dim3(32, 8, 3), 256, 0, stream>>>(
        x, wq, wk, wv, qp, kp, qp /*unused*/, vt);
    // 2. RoPE in place on q and k (bf16)
    rope_inplace<<<dim3(8192), 256, 0, stream>>>(qp, kp);
    // 3. causal flash attention (XCD-swizzled); output in-place into qp
    attn_kernel<<<dim3(512), 256, 0, stream>>>(qp, kp, vt);
    // 4. output projection: qp (bf16) x wo (fp32) -> d_out (fp32)
    gemm_bt<bf16, float, float><<<dim3(32, 8, 1), 256, 0, stream>>>(
        qp, wo, wo, wo, out, out, out, nullptr);
}